// Round 7
// baseline (104.301 us; speedup 1.0000x reference)
//
#include <hip/hip_runtime.h>

#define BATCH 32

typedef float f32x4 __attribute__((ext_vector_type(4)));

// ---------------------------------------------------------------------------
// Kernel 1: per-batch scan of dur + scatter of the output-row -> source-frame
// table. src[b][t] = frame index feeding output row t, or -1 for padded tail.
// One block of T=1024 threads per batch row. ~480 KB table in d_ws.
// ---------------------------------------------------------------------------
__global__ void build_src_kernel(const int* __restrict__ dur,
                                 int* __restrict__ src,
                                 int T, int max_len) {
    const int b = blockIdx.x;
    const int tid = threadIdx.x;          // 0..T-1
    const int lane = tid & 63;
    const int w = tid >> 6;               // 0..15

    __shared__ int part[16];
    __shared__ int totsh;

    const int d = dur[b * T + tid];
    int v = d;
    #pragma unroll
    for (int off = 1; off < 64; off <<= 1) {
        int u = __shfl_up(v, off, 64);
        if (lane >= off) v += u;
    }
    if (lane == 63) part[w] = v;
    __syncthreads();
    if (w == 0 && lane < 16) {
        int p = part[lane];
        #pragma unroll
        for (int off = 1; off < 16; off <<= 1) {
            int u = __shfl_up(p, off, 16);
            if (lane >= off) p += u;
        }
        part[lane] = p;
    }
    __syncthreads();

    const int end = v + (w > 0 ? part[w - 1] : 0);  // inclusive cumsum at tid
    const int start = end - d;
    if (tid == T - 1) totsh = end;

    int* __restrict__ srow = src + (size_t)b * max_len;
    for (int j = start; j < end; ++j) srow[j] = tid;   // disjoint ranges, race-free
    __syncthreads();

    const int total = totsh;
    for (int i = total + tid; i < max_len; i += blockDim.x) srow[i] = -1;
}

// ---------------------------------------------------------------------------
// Kernel 2: fill-kernel-shaped expand. 2048 blocks x 256 threads = 8192 waves,
// all co-resident (8 blocks/CU). Each wave owns a CONTIGUOUS chunk of output
// rows and streams stores row after row (uninterrupted write stream, like the
// harness fill). x is reloaded only when the source frame changes (~1 per 3.5
// rows); src reads are wave-uniform L1 hits.
// ---------------------------------------------------------------------------
__global__ void expand_rows_kernel(const float* __restrict__ x,
                                   const int* __restrict__ src,
                                   float* __restrict__ out,
                                   int T, int D, int max_len, int rows_per_wave) {
    const int lane = threadIdx.x & 63;
    const int wid = (int)((blockIdx.x * blockDim.x + threadIdx.x) >> 6);

    const long R = (long)BATCH * max_len;
    long r0 = (long)wid * rows_per_wave;
    if (r0 >= R) return;
    long r1 = r0 + rows_per_wave;
    if (r1 > R) r1 = R;

    int b = (int)(r0 / max_len);
    int t = (int)(r0 - (long)b * max_len);

    const int* __restrict__ srow = src + (size_t)b * max_len;
    int sprev = -2;
    f32x4 v0 = (f32x4)(0.f), v1 = (f32x4)(0.f), v2 = (f32x4)(0.f);

    for (long r = r0; r < r1; ++r) {
        const int s = srow[t];
        if (s != sprev) {
            if (s >= 0) {
                const f32x4* __restrict__ sp =
                    reinterpret_cast<const f32x4*>(x + ((size_t)b * T + s) * D);
                v0 = sp[lane];
                v1 = sp[lane + 64];
                v2 = sp[lane + 128];
            } else {
                v0 = (f32x4)(0.f); v1 = (f32x4)(0.f); v2 = (f32x4)(0.f);
            }
            sprev = s;
        }
        f32x4* __restrict__ dst =
            reinterpret_cast<f32x4*>(out + ((size_t)b * max_len + t) * D);
        dst[lane]       = v0;
        dst[lane + 64]  = v1;
        dst[lane + 128] = v2;

        if (++t == max_len) {      // batch wrap
            t = 0;
            ++b;
            srow = src + (size_t)b * max_len;
            sprev = -2;
        }
    }
}

extern "C" void kernel_launch(void* const* d_in, const int* in_sizes, int n_in,
                              void* d_out, int out_size, void* d_ws, size_t ws_size,
                              hipStream_t stream) {
    const float* x = (const float*)d_in[0];
    const int* dur = (const int*)d_in[1];
    float* out = (float*)d_out;

    const int BT = in_sizes[1];          // B*T
    const int B = BATCH;
    const int T = BT / B;                // 1024
    const int D = in_sizes[0] / BT;      // 768
    const int max_len = out_size / (B * D);

    int* src = (int*)d_ws;               // B * max_len ints (~480 KB)

    build_src_kernel<<<B, T, 0, stream>>>(dur, src, T, max_len);

    const int nblocks = 2048;            // 8 blocks/CU, all resident
    const int nwaves = nblocks * 4;      // 256 threads = 4 waves/block
    const long R = (long)B * max_len;
    const int rows_per_wave = (int)((R + nwaves - 1) / nwaves);

    expand_rows_kernel<<<nblocks, 256, 0, stream>>>(x, src, out, T, D, max_len,
                                                    rows_per_wave);
}

// Round 8
// 94.835 us; speedup vs baseline: 1.0998x; 1.0998x over previous
//
#include <hip/hip_runtime.h>

#define BATCH 32

typedef float f32x4 __attribute__((ext_vector_type(4)));
typedef int   i32x4 __attribute__((ext_vector_type(4)));

// ---------------------------------------------------------------------------
// Single fused kernel (R6 structure). Block = (64,4) = 4 waves, grid = (T/4, B).
// A/B vs R6: stores are NON-TEMPORAL (out is a 353MB write-once stream, 11x L2;
// avoid L2 write-allocate/evict churn). Loads of x stay NT too (read-once).
//
// Each block computes the inclusive cumsum of dur[b][0..T) in LDS. Wave
// handling frame r:
//   1. expand: load frame r once (3 x 16B NT loads/lane), NT-store to output
//      rows [cs[r-1], cs[r]).
//   2. tail zero-fill: rows total + r + k*T (stride-T) — each padded row
//      covered by exactly one wave.
// ---------------------------------------------------------------------------
__global__ void lr_fused_kernel(const float* __restrict__ x,
                                const int* __restrict__ dur,
                                float* __restrict__ out,
                                int T, int D, int max_len) {
    const int b = blockIdx.y;
    const int tid = threadIdx.y * 64 + threadIdx.x;  // 0..255
    const int lane = tid & 63;
    const int w = tid >> 6;                          // wave id 0..3

    __shared__ int cs[1024];   // T = 1024
    __shared__ int part[4];

    // --- block-wide inclusive scan of the dur row (4 ints per thread) ---
    const i32x4* __restrict__ drow = reinterpret_cast<const i32x4*>(dur + b * T);
    const i32x4 d = drow[tid];
    const int s0 = d.x;
    const int s1 = s0 + d.y;
    const int s2 = s1 + d.z;
    const int s3 = s2 + d.w;

    int v = s3;                                      // wave-inclusive scan of thread sums
    #pragma unroll
    for (int off = 1; off < 64; off <<= 1) {
        int u = __shfl_up(v, off, 64);
        if (lane >= off) v += u;
    }
    if (lane == 63) part[w] = v;
    __syncthreads();

    int add = 0;
    if (w > 0) add += part[0];
    if (w > 1) add += part[1];
    if (w > 2) add += part[2];

    const int base = add + v - s3;                   // exclusive prefix for this thread
    cs[tid * 4 + 0] = base + s0;
    cs[tid * 4 + 1] = base + s1;
    cs[tid * 4 + 2] = base + s2;
    cs[tid * 4 + 3] = base + s3;
    __syncthreads();

    const int r = blockIdx.x * 4 + w;                // source frame, 0..T-1
    const int d4 = D >> 2;                           // 192
    const int total = cs[T - 1];

    if (r < T) {
        const int end = cs[r];
        const int start = (r == 0) ? 0 : cs[r - 1];
        if (start != end) {                          // dur > 0
            const f32x4* __restrict__ sp =
                reinterpret_cast<const f32x4*>(x + ((size_t)b * T + r) * D);
            const f32x4 v0 = __builtin_nontemporal_load(&sp[lane]);
            const f32x4 v1 = __builtin_nontemporal_load(&sp[lane + 64]);
            const f32x4 v2 = __builtin_nontemporal_load(&sp[lane + 128]);

            f32x4* __restrict__ dst =
                reinterpret_cast<f32x4*>(out + ((size_t)b * max_len + start) * D);
            for (int j = start; j < end; ++j) {
                __builtin_nontemporal_store(v0, &dst[lane]);
                __builtin_nontemporal_store(v1, &dst[lane + 64]);
                __builtin_nontemporal_store(v2, &dst[lane + 128]);
                dst += d4;
            }
        }

        // --- tail zero-fill ---
        const f32x4 z = (f32x4)(0.f);
        for (int t = total + r; t < max_len; t += T) {
            f32x4* __restrict__ zp =
                reinterpret_cast<f32x4*>(out + ((size_t)b * max_len + t) * D);
            __builtin_nontemporal_store(z, &zp[lane]);
            __builtin_nontemporal_store(z, &zp[lane + 64]);
            __builtin_nontemporal_store(z, &zp[lane + 128]);
        }
    }
}

extern "C" void kernel_launch(void* const* d_in, const int* in_sizes, int n_in,
                              void* d_out, int out_size, void* d_ws, size_t ws_size,
                              hipStream_t stream) {
    const float* x = (const float*)d_in[0];
    const int* dur = (const int*)d_in[1];
    float* out = (float*)d_out;

    const int BT = in_sizes[1];          // B*T
    const int B = BATCH;
    const int T = BT / B;                // 1024
    const int D = in_sizes[0] / BT;      // 768
    const int max_len = out_size / (B * D);

    dim3 block(64, 4);
    dim3 grid((T + 3) / 4, B);
    lr_fused_kernel<<<grid, block, 0, stream>>>(x, dur, out, T, D, max_len);
}

// Round 9
// 94.653 us; speedup vs baseline: 1.1019x; 1.0019x over previous
//
#include <hip/hip_runtime.h>

#define BATCH 32
#define FPW 4   // frames per wave

typedef float f32x4 __attribute__((ext_vector_type(4)));
typedef int   i32x4 __attribute__((ext_vector_type(4)));

// ---------------------------------------------------------------------------
// Single kernel, fill-kernel-shaped. Block = (64,4) = 4 waves; each wave owns
// FPW=4 CONSECUTIVE source frames; grid = (T/(4*FPW), B) = (64, 32) = 2048
// blocks = exactly 8/CU, fully resident, no churn.
//
// Per block: R6's LDS scan of the dur row (now only 2048 scans total, was
// 8192). Per wave: 2-stage pipeline over its 4 frames — issue NT load of
// frame k+1 BEFORE streaming frame k's stores, so HBM load latency hides
// under the store stream. All extents register/LDS-resident: no per-row
// lookups in the store stream (R7's mistake).
// ---------------------------------------------------------------------------
__global__ __launch_bounds__(256, 8)
void lr_stream_kernel(const float* __restrict__ x,
                      const int* __restrict__ dur,
                      float* __restrict__ out,
                      int T, int D, int max_len) {
    const int b = blockIdx.y;
    const int bx = blockIdx.x;                       // 0..T/16-1
    const int tid = threadIdx.y * 64 + threadIdx.x;  // 0..255
    const int lane = tid & 63;
    const int w = tid >> 6;                          // wave id 0..3

    __shared__ int cs[1024];   // T = 1024
    __shared__ int part[4];

    // --- block-wide inclusive scan of the dur row (4 ints per thread) ---
    const i32x4 d = reinterpret_cast<const i32x4*>(dur + b * T)[tid];
    const int s0 = d.x;
    const int s1 = s0 + d.y;
    const int s2 = s1 + d.z;
    const int s3 = s2 + d.w;

    int v = s3;
    #pragma unroll
    for (int off = 1; off < 64; off <<= 1) {
        int u = __shfl_up(v, off, 64);
        if (lane >= off) v += u;
    }
    if (lane == 63) part[w] = v;
    __syncthreads();

    int add = 0;
    if (w > 0) add += part[0];
    if (w > 1) add += part[1];
    if (w > 2) add += part[2];

    const int base = add + v - s3;
    cs[tid * 4 + 0] = base + s0;
    cs[tid * 4 + 1] = base + s1;
    cs[tid * 4 + 2] = base + s2;
    cs[tid * 4 + 3] = base + s3;
    __syncthreads();

    const int total = cs[T - 1];
    const int d4 = D >> 2;                           // 192

    // --- this wave's 4 consecutive frames and their output extents ---
    const int fbase = (bx * 4 + w) * FPW;
    int st[FPW + 1];
    st[0] = (fbase == 0) ? 0 : cs[fbase - 1];
    #pragma unroll
    for (int k = 0; k < FPW; ++k) st[k + 1] = cs[fbase + k];

    const f32x4* __restrict__ xb =
        reinterpret_cast<const f32x4*>(x + (size_t)b * T * D);

    // --- 2-stage pipelined expand ---
    f32x4 a0, a1, a2, n0, n1, n2;
    if (st[1] > st[0]) {                             // preload frame 0
        const f32x4* sp = xb + (size_t)fbase * d4;
        a0 = __builtin_nontemporal_load(&sp[lane]);
        a1 = __builtin_nontemporal_load(&sp[lane + 64]);
        a2 = __builtin_nontemporal_load(&sp[lane + 128]);
    }
    #pragma unroll
    for (int k = 0; k < FPW; ++k) {
        if (k + 1 < FPW && st[k + 2] > st[k + 1]) {  // issue next load early
            const f32x4* sp = xb + (size_t)(fbase + k + 1) * d4;
            n0 = __builtin_nontemporal_load(&sp[lane]);
            n1 = __builtin_nontemporal_load(&sp[lane + 64]);
            n2 = __builtin_nontemporal_load(&sp[lane + 128]);
        }
        f32x4* __restrict__ dst =
            reinterpret_cast<f32x4*>(out + ((size_t)b * max_len + st[k]) * D);
        for (int j = st[k]; j < st[k + 1]; ++j) {    // stream current frame
            __builtin_nontemporal_store(a0, &dst[lane]);
            __builtin_nontemporal_store(a1, &dst[lane + 64]);
            __builtin_nontemporal_store(a2, &dst[lane + 128]);
            dst += d4;
        }
        a0 = n0; a1 = n1; a2 = n2;                   // rotate pipeline
    }

    // --- tail zero-fill: waves of this batch stripe rows past total ---
    const int q = bx * 4 + w;                        // 0..255 within batch
    const int nq = (T / (4 * FPW)) * 4;              // 256 waves per batch
    const f32x4 z = (f32x4)(0.f);
    for (int t = total + q; t < max_len; t += nq) {
        f32x4* __restrict__ zp =
            reinterpret_cast<f32x4*>(out + ((size_t)b * max_len + t) * D);
        __builtin_nontemporal_store(z, &zp[lane]);
        __builtin_nontemporal_store(z, &zp[lane + 64]);
        __builtin_nontemporal_store(z, &zp[lane + 128]);
    }
}

extern "C" void kernel_launch(void* const* d_in, const int* in_sizes, int n_in,
                              void* d_out, int out_size, void* d_ws, size_t ws_size,
                              hipStream_t stream) {
    const float* x = (const float*)d_in[0];
    const int* dur = (const int*)d_in[1];
    float* out = (float*)d_out;

    const int BT = in_sizes[1];          // B*T
    const int B = BATCH;
    const int T = BT / B;                // 1024
    const int D = in_sizes[0] / BT;      // 768
    const int max_len = out_size / (B * D);

    dim3 block(64, 4);
    dim3 grid(T / (4 * FPW), B);         // (64, 32) = 2048 blocks
    lr_stream_kernel<<<grid, block, 0, stream>>>(x, dur, out, T, D, max_len);
}